// Round 15
// baseline (904.531 us; speedup 1.0000x reference)
//
#include <hip/hip_runtime.h>

#define TSEQ 512
#define FUT  16
#define OT   (TSEQ + FUT)
#define NB   8            // batch rows per block; grid = 4096/8 = 512 -> 2 blocks/CU
#define NWAVE 7
#define NTHREADS (NWAVE * 64)
#define OBS  20

typedef _Float16 f16x8 __attribute__((ext_vector_type(8)));
typedef float    f32x4 __attribute__((ext_vector_type(4)));

#define NL2E  (-1.44269504089f)
#define N2L2E (-2.88539008178f)

__device__ __forceinline__ f32x4 mfma16(f16x8 a, f16x8 b, f32x4 c) {
    return __builtin_amdgcn_mfma_f32_16x16x32_f16(a, b, c, 0, 0, 0);
}

// single-instruction 2^x (v_exp_f32)
__device__ __forceinline__ float exp2fast(float x) {
#if __has_builtin(__builtin_amdgcn_exp2f)
    return __builtin_amdgcn_exp2f(x);
#else
    float r;
    asm("v_exp_f32 %0, %1\n\ts_nop 1" : "=v"(r) : "v"(x));
    return r;
#endif
}

// main-loop barrier: order LDS only (lgkmcnt); vmcnt stays un-drained so
// x-loads / o-stores ride across barriers (their waits land at use).
#define BAR_LGKM() asm volatile("s_waitcnt lgkmcnt(0)\n\ts_barrier" ::: "memory")

// acc pre-scaled at weight-load: i,f,o rows by -log2e; g row by -2log2e.
// sig(x) = rcp(1+E), tanh via (1-E)/(1+E); fused denominators: 5 exp + 3 rcp.
__device__ __forceinline__ float cell2(const f32x4 acc, float& c) {
    const float Ei = exp2fast(acc[0]);          // e^-i
    const float Ef = exp2fast(acc[1]);          // e^-f
    const float Eg = exp2fast(acc[2]);          // e^-2g
    const float Eo = exp2fast(acc[3]);          // e^-o
    const float sf   = __builtin_amdgcn_rcpf(1.0f + Ef);
    const float sitg = (1.0f - Eg) * __builtin_amdgcn_rcpf((1.0f + Ei) * (1.0f + Eg));
    c = fmaf(sf, c, sitg);
    const float Ec = exp2fast(c * N2L2E);       // e^-2c
    return (1.0f - Ec) * __builtin_amdgcn_rcpf((1.0f + Eo) * (1.0f + Ec));
}

__global__ __launch_bounds__(NTHREADS, 2) void lstm_mfma_kernel(
    const float* __restrict__ input,   // [B, 512]
    const float* __restrict__ W_ih1,   // [204,1]
    const float* __restrict__ W_hh1,   // [204,51]
    const float* __restrict__ b_ih1,
    const float* __restrict__ b_hh1,
    const float* __restrict__ W_ih2,   // [204,51]
    const float* __restrict__ W_hh2,   // [204,51]
    const float* __restrict__ b_ih2,
    const float* __restrict__ b_hh2,
    const float* __restrict__ W_lin,   // [1,51]
    const float* __restrict__ b_lin,
    float* __restrict__ out)           // [B, 528]
{
    const int tid  = threadIdx.x;
    const int w    = tid >> 6;    // wave id (0..6)
    const int lane = tid & 63;
    const int n    = lane & 15;   // MFMA column (batch col for n<NB; ghost else)
    const int q    = lane >> 4;   // k-group / unit-in-tile
    const int b0   = blockIdx.x * NB;
    const bool bok = (n < NB);            // lane maps to a real batch row
    const int bidx = b0 + (n & (NB - 1)); // clamped batch index (safe loads;
                                          // ghost cols duplicate col n&7 -> bounded)

    // wave w handles gate-tiles tA = w and tB = w+7 (wave 6: tA only)
    const int tA = w;
    const int tB = w + 7;
    const bool hasB = (w < 6);

    // activations (hi f16) in MFMA B-fragment layout, parity double-buffered
    // logical k at [k>>5][n + 16*((k&31)>>3)][k&7]; H1 k=51 slot carries x_t
    __shared__ _Float16 H1[2][2][64][8] __attribute__((aligned(16)));
    __shared__ _Float16 H2[2][2][64][8] __attribute__((aligned(16)));
    __shared__ float OB[2][16][OBS] __attribute__((aligned(16)));

    const float rsc = ((n & 3) == 2) ? N2L2E : NL2E;  // exp2 fold (g row: -2log2e)

    f16x8 W1hA[2], W1lA[2], W2hA[4], W2lA[4];
    f16x8 W1hB[2], W1lB[2], W2hB[4], W2lB[4];

#define LOADW(TT, W1h, W1l, W2h, W2l)                                          \
    {                                                                          \
        const int ru = 4 * (TT) + (n >> 2);                                    \
        const bool rv = (ru < 51);                                             \
        const int R = 51 * (n & 3) + (rv ? ru : 50);                           \
        const bool olin = ((TT) == 12) && (n == 12);                           \
        _Pragma("unroll")                                                      \
        for (int s = 0; s < 2; ++s) {                                          \
            _Pragma("unroll")                                                  \
            for (int e = 0; e < 8; ++e) {                                      \
                const int k = 32 * s + 8 * q + e;                              \
                float wv = 0.0f;                                               \
                if (rv) {                                                      \
                    if (k < 51)       wv = rsc * W_hh1[R * 51 + k];            \
                    else if (k == 51) wv = rsc * W_ih1[R];                     \
                }                                                              \
                const _Float16 hi = (_Float16)wv;                              \
                W1h[s][e] = hi;                                                \
                W1l[s][e] = (_Float16)(wv - (float)hi);                        \
            }                                                                  \
        }                                                                      \
        _Pragma("unroll")                                                      \
        for (int s = 0; s < 4; ++s) {                                          \
            _Pragma("unroll")                                                  \
            for (int e = 0; e < 8; ++e) {                                      \
                const int k = 32 * s + 8 * q + e;                              \
                float wv = 0.0f;                                               \
                if (rv) {                                                      \
                    if (k < 51)                  wv = rsc * W_ih2[R * 51 + k]; \
                    else if (k >= 64 && k < 115) wv = rsc * W_hh2[R * 51 + (k - 64)]; \
                } else if (olin) {                                             \
                    if (k >= 64 && k < 115)      wv = W_lin[k - 64];           \
                }                                                              \
                const _Float16 hi = (_Float16)wv;                              \
                W2h[s][e] = hi;                                                \
                W2l[s][e] = (_Float16)(wv - (float)hi);                        \
            }                                                                  \
        }                                                                      \
    }

    LOADW(tA, W1hA, W1lA, W2hA, W2lA)
    LOADW(tB, W1hB, W1lB, W2hB, W2lB)   // tB=13 for w6 -> all zeros (unused)
#undef LOADW

    // ---- update-side constants ----
    const int uuA = 4 * tA + q;
    const int uuB = 4 * tB + q;
    const bool ustA = (uuA < 51);
    const bool ustB = (uuB < 51) && hasB;
    const bool oduty = (w == 5) && (q == 3);   // tile-12 W_lin row -> b2[0] = o
    const float blin = b_lin[0];

    f32x4 bias1A, bias2A, bias1B, bias2B;
#pragma unroll
    for (int r = 0; r < 4; ++r) {
        const float s = (r == 2) ? N2L2E : NL2E;
        const int rowA = 51 * r + (ustA ? uuA : 50);
        bias1A[r] = ustA ? s * (b_ih1[rowA] + b_hh1[rowA]) : 0.0f;
        bias2A[r] = ustA ? s * (b_ih2[rowA] + b_hh2[rowA]) : 0.0f;
        const int rowB = 51 * r + (ustB ? uuB : 50);
        bias1B[r] = ustB ? s * (b_ih1[rowB] + b_hh1[rowB]) : 0.0f;
        bias2B[r] = ustB ? s * (b_ih2[rowB] + b_hh2[rowB]) : 0.0f;
    }
    if (oduty) bias2B[0] = blin;               // C-init of the W_lin row

    const float wlinA = ustA ? W_lin[uuA] : 0.0f;
    const float wlinB = ustB ? W_lin[uuB] : 0.0f;

    // h-store coords; pad lanes redirect to fake unit 60 (zero-weight k-slot)
    const int uuXA = ustA ? uuA : 60;
    const int usA = uuXA >> 5, lpA = n + 16 * ((uuXA & 31) >> 3), ueA = uuXA & 7;
    const int uuXB = ustB ? uuB : 60;
    const int usB = uuXB >> 5, lpB = n + 16 * ((uuXB & 31) >> 3), ueB = uuXB & 7;

    // ---- zero activation LDS ----
    {
        const f16x8 zz = {0, 0, 0, 0, 0, 0, 0, 0};
        f16x8* p1 = (f16x8*)&H1[0][0][0][0];
        f16x8* p2 = (f16x8*)&H2[0][0][0][0];
        for (int i = tid; i < 2 * 2 * 64; i += NTHREADS) { p1[i] = zz; p2[i] = zz; }
    }
    __syncthreads();

    float c1A = 0.0f, c2A = 0.0f, c1B = 0.0f, c2B = 0.0f;

    // x chunks live on wave 6 (lightest) q2 lanes
    f32x4 xv = {0, 0, 0, 0}, xvn = {0, 0, 0, 0};
    if (w == 6 && q == 2) {
        xv  = *(const f32x4*)&input[bidx * TSEQ + 0];
        xvn = *(const f32x4*)&input[bidx * TSEQ + 4];
    }

    // batched o-store buffer (meaningful on oduty lanes only)
    f32x4 obuf = {0, 0, 0, 0};

    // ---- prologue: phase 0 = L1(0) with h1_{-1}=0; seed x_1 into H1[1] ----
    {
        const float x0 = input[bidx * TSEQ + 0];
        if (w == 6 && q == 2) H1[1][1][32 + n][3] = (_Float16)xv[1];  // x_1
        f16x8 xf = {0,0,0,0,0,0,0,0};
        if (q == 2) xf[3] = (_Float16)x0;
        f32x4 a1 = mfma16(W1hA[1], xf, bias1A);
        a1 = mfma16(W1lA[1], xf, a1);
        const float h1A = cell2(a1, c1A);
        H1[1][usA][lpA][ueA] = (_Float16)h1A;
        if (hasB) {
            f32x4 b1 = mfma16(W1hB[1], xf, bias1B);
            b1 = mfma16(W1lB[1], xf, b1);
            const float h1B = cell2(b1, c1B);
            H1[1][usB][lpB][ueB] = (_Float16)h1B;
        }
    }
    __syncthreads();

    // ---- main loop: phase t does L1(t) || L2(t-1) for both tiles, 1 barrier ----
#define PHASE(t_, W_, ROT_, OSL_, OSTORE_, FLUSH_, LOADN_, XW_)                \
    {                                                                          \
        const int p_  = (t_) & 1;                                              \
        const int pn_ = p_ ^ 1;                                                \
        const f16x8 h1k0 = *(const f16x8*)&H1[p_][0][lane][0];                 \
        const f16x8 h1k1 = *(const f16x8*)&H1[p_][1][lane][0];                 \
        const f16x8 h2k0 = *(const f16x8*)&H2[p_][0][lane][0];                 \
        const f16x8 h2k1 = *(const f16x8*)&H2[p_][1][lane][0];                 \
        if (w == 6) {                                                          \
            if (ROT_) xv = xvn;                                                \
            if ((LOADN_) && q == 2)                                            \
                xvn = *(const f32x4*)&input[bidx * TSEQ + (t_) + 3];           \
            if ((XW_) && q == 2)                                               \
                H1[pn_][1][32 + n][3] = (_Float16)xv[W_];                      \
        }                                                                      \
        f32x4 a1 = mfma16(W1hA[0], h1k0, bias1A);                              \
        a1 = mfma16(W1lA[0], h1k0, a1);                                        \
        a1 = mfma16(W1hA[1], h1k1, a1);                                        \
        a1 = mfma16(W1lA[1], h1k1, a1);                                        \
        f32x4 a2 = mfma16(W2hA[0], h1k0, bias2A);                              \
        a2 = mfma16(W2lA[0], h1k0, a2);                                        \
        a2 = mfma16(W2hA[1], h1k1, a2);                                        \
        a2 = mfma16(W2lA[1], h1k1, a2);                                        \
        a2 = mfma16(W2hA[2], h2k0, a2);                                        \
        a2 = mfma16(W2lA[2], h2k0, a2);                                        \
        a2 = mfma16(W2hA[3], h2k1, a2);                                        \
        a2 = mfma16(W2lA[3], h2k1, a2);                                        \
        const float h1nA = cell2(a1, c1A);                                     \
        const float h2nA = cell2(a2, c2A);                                     \
        H1[pn_][usA][lpA][ueA] = (_Float16)h1nA;                               \
        H2[pn_][usA][lpA][ueA] = (_Float16)h2nA;                               \
        if (hasB) {                                                            \
            f32x4 b1 = mfma16(W1hB[0], h1k0, bias1B);                          \
            b1 = mfma16(W1lB[0], h1k0, b1);                                    \
            b1 = mfma16(W1hB[1], h1k1, b1);                                    \
            b1 = mfma16(W1lB[1], h1k1, b1);                                    \
            f32x4 b2 = mfma16(W2hB[0], h1k0, bias2B);                          \
            b2 = mfma16(W2lB[0], h1k0, b2);                                    \
            b2 = mfma16(W2hB[1], h1k1, b2);                                    \
            b2 = mfma16(W2lB[1], h1k1, b2);                                    \
            b2 = mfma16(W2hB[2], h2k0, b2);                                    \
            b2 = mfma16(W2lB[2], h2k0, b2);                                    \
            b2 = mfma16(W2hB[3], h2k1, b2);                                    \
            b2 = mfma16(W2lB[3], h2k1, b2);                                    \
            if (OSTORE_) obuf[OSL_] = b2[0];                                   \
            if ((FLUSH_) && oduty && bok)                                      \
                *reinterpret_cast<f32x4*>(&out[(b0 + n) * OT + (t_) - 5]) = obuf; \
            const float h1nB = cell2(b1, c1B);                                 \
            const float h2nB = cell2(b2, c2B);                                 \
            H1[pn_][usB][lpB][ueB] = (_Float16)h1nB;                           \
            H2[pn_][usB][lpB][ueB] = (_Float16)h2nB;                           \
        }                                                                      \
        BAR_LGKM();                                                            \
    }

    //      t    W  ROT OSL OST FLU LOD XW
    PHASE(  1,   2, 0,  0,  0,  0,  0,  1)   // writes x_2
    for (int tb = 2; tb + 3 <= 505; tb += 4) {
        PHASE(tb + 0, 3, 0, 0, 1, 0, 0, 1)   // o_{tb-2} slot0; writes x_{tb+1}
        PHASE(tb + 1, 0, 1, 1, 1, 0, 0, 1)   // rotate; writes x_{tb+2}
        PHASE(tb + 2, 1, 0, 2, 1, 0, 0, 1)
        PHASE(tb + 3, 2, 0, 3, 1, 1, 1, 1)   // flush o_{tb-2..tb+1}; load chunk
    }
    PHASE(506, 3, 0, 0, 1, 0, 0, 1)          // o_504; writes x_507
    PHASE(507, 0, 1, 1, 1, 0, 0, 1)          // o_505; rotate; writes x_508
    PHASE(508, 1, 0, 2, 1, 0, 0, 1)          // o_506; writes x_509
    PHASE(509, 2, 0, 3, 1, 1, 0, 1)          // o_507 + flush o_504..507; writes x_510
    PHASE(510, 3, 0, 0, 1, 0, 0, 1)          // o_508 -> slot0; writes x_511
    PHASE(511, 0, 0, 1, 1, 0, 0, 0)          // o_509 -> slot1; no x write
#undef PHASE

    if (oduty && bok) {                      // flush o_508, o_509
        out[(b0 + n) * OT + 508] = obuf[0];
        out[(b0 + n) * OT + 509] = obuf[1];
    }

    // ---- tail: autoregressive steps t = 512..527 (x_t = o_{t-1}) ----
    for (int t = TSEQ; t < OT; ++t) {
        const int p  = t & 1;
        const int pn = p ^ 1;

        // .a: L2(t-1) -> h2_{t-1}; OB partials; o_510 via MFMA row at t==512
        const f16x8 h1k0 = *(const f16x8*)&H1[p][0][lane][0];
        f16x8 h1k1       = *(const f16x8*)&H1[p][1][lane][0];
        const f16x8 h2k0 = *(const f16x8*)&H2[p][0][lane][0];
        const f16x8 h2k1 = *(const f16x8*)&H2[p][1][lane][0];
        f32x4 a2 = mfma16(W2hA[0], h1k0, bias2A);
        a2 = mfma16(W2lA[0], h1k0, a2);
        a2 = mfma16(W2hA[1], h1k1, a2);
        a2 = mfma16(W2lA[1], h1k1, a2);
        a2 = mfma16(W2hA[2], h2k0, a2);
        a2 = mfma16(W2lA[2], h2k0, a2);
        a2 = mfma16(W2hA[3], h2k1, a2);
        a2 = mfma16(W2lA[3], h2k1, a2);
        const float h2nA = cell2(a2, c2A);
        H2[pn][usA][lpA][ueA] = (_Float16)h2nA;
        float poA = h2nA * wlinA;
        poA += __shfl_xor(poA, 16, 64);
        poA += __shfl_xor(poA, 32, 64);
        if (lane < 16) OB[p][lane][tA] = poA;
        if (hasB) {
            f32x4 b2 = mfma16(W2hB[0], h1k0, bias2B);
            b2 = mfma16(W2lB[0], h1k0, b2);
            b2 = mfma16(W2hB[1], h1k1, b2);
            b2 = mfma16(W2lB[1], h1k1, b2);
            b2 = mfma16(W2hB[2], h2k0, b2);
            b2 = mfma16(W2lB[2], h2k0, b2);
            b2 = mfma16(W2hB[3], h2k1, b2);
            b2 = mfma16(W2lB[3], h2k1, b2);
            if (oduty && bok && t == TSEQ) out[(b0 + n) * OT + (TSEQ - 2)] = b2[0];  // o_510
            const float h2nB = cell2(b2, c2B);
            H2[pn][usB][lpB][ueB] = (_Float16)h2nB;
            float poB = h2nB * wlinB;
            poB += __shfl_xor(poB, 16, 64);
            poB += __shfl_xor(poB, 32, 64);
            if (lane < 16) OB[p][lane][tB] = poB;
        }
        __syncthreads();

        // .b: finalize o_{t-1} (q2 lanes, redundant per wave); feedback; L1(t)
        float xcur = 0.0f;
        if (q == 2) {
            const float* ob = &OB[p][n][0];
            const f32x4 s0 = *(const f32x4*)&ob[0];
            const f32x4 s1 = *(const f32x4*)&ob[4];
            const f32x4 s2 = *(const f32x4*)&ob[8];
            const float o = ((s0[0] + s0[1]) + (s0[2] + s0[3]))
                          + ((s1[0] + s1[1]) + (s1[2] + s1[3]))
                          + ((s2[0] + s2[1]) + (s2[2] + s2[3])) + ob[12] + blin;
            if (w == 0 && bok) out[(b0 + n) * OT + (t - 1)] = o;
            xcur = o;
        }
        if (q == 2) h1k1[3] = (_Float16)xcur;   // patch x_t (f16)
        f32x4 a1 = mfma16(W1hA[0], h1k0, bias1A);
        a1 = mfma16(W1lA[0], h1k0, a1);
        a1 = mfma16(W1hA[1], h1k1, a1);
        a1 = mfma16(W1lA[1], h1k1, a1);
        const float h1nA = cell2(a1, c1A);
        H1[pn][usA][lpA][ueA] = (_Float16)h1nA;
        if (hasB) {
            f32x4 b1 = mfma16(W1hB[0], h1k0, bias1B);
            b1 = mfma16(W1lB[0], h1k0, b1);
            b1 = mfma16(W1hB[1], h1k1, b1);
            b1 = mfma16(W1lB[1], h1k1, b1);
            const float h1nB = cell2(b1, c1B);
            H1[pn][usB][lpB][ueB] = (_Float16)h1nB;
        }
        __syncthreads();
    }

    // ---- final: L2(527) -> h2_527 -> o_527 ----
    {
        const f16x8 h1k0 = *(const f16x8*)&H1[0][0][lane][0];
        const f16x8 h1k1 = *(const f16x8*)&H1[0][1][lane][0];
        const f16x8 h2k0 = *(const f16x8*)&H2[0][0][lane][0];
        const f16x8 h2k1 = *(const f16x8*)&H2[0][1][lane][0];
        f32x4 a2 = mfma16(W2hA[0], h1k0, bias2A);
        a2 = mfma16(W2lA[0], h1k0, a2);
        a2 = mfma16(W2hA[1], h1k1, a2);
        a2 = mfma16(W2lA[1], h1k1, a2);
        a2 = mfma16(W2hA[2], h2k0, a2);
        a2 = mfma16(W2lA[2], h2k0, a2);
        a2 = mfma16(W2hA[3], h2k1, a2);
        a2 = mfma16(W2lA[3], h2k1, a2);
        const float h2nA = cell2(a2, c2A);
        float poA = h2nA * wlinA;
        poA += __shfl_xor(poA, 16, 64);
        poA += __shfl_xor(poA, 32, 64);
        if (lane < 16) OB[0][lane][tA] = poA;
        if (hasB) {
            f32x4 b2 = mfma16(W2hB[0], h1k0, bias2B);
            b2 = mfma16(W2lB[0], h1k0, b2);
            b2 = mfma16(W2hB[1], h1k1, b2);
            b2 = mfma16(W2lB[1], h1k1, b2);
            b2 = mfma16(W2hB[2], h2k0, b2);
            b2 = mfma16(W2lB[2], h2k0, b2);
            b2 = mfma16(W2hB[3], h2k1, b2);
            b2 = mfma16(W2lB[3], h2k1, b2);
            const float h2nB = cell2(b2, c2B);
            float poB = h2nB * wlinB;
            poB += __shfl_xor(poB, 16, 64);
            poB += __shfl_xor(poB, 32, 64);
            if (lane < 16) OB[0][lane][tB] = poB;
        }
        __syncthreads();
        if (w == 0 && lane < NB) {
            const float* ob = &OB[0][lane][0];
            const f32x4 s0 = *(const f32x4*)&ob[0];
            const f32x4 s1 = *(const f32x4*)&ob[4];
            const f32x4 s2 = *(const f32x4*)&ob[8];
            out[(b0 + lane) * OT + (OT - 1)] =
                ((s0[0] + s0[1]) + (s0[2] + s0[3])) +
                ((s1[0] + s1[1]) + (s1[2] + s1[3])) +
                ((s2[0] + s2[1]) + (s2[2] + s2[3])) + ob[12] + blin;
        }
    }
}

extern "C" void kernel_launch(void* const* d_in, const int* in_sizes, int n_in,
                              void* d_out, int out_size, void* d_ws, size_t ws_size,
                              hipStream_t stream) {
    const float* input = (const float*)d_in[0];
    const float* W_ih1 = (const float*)d_in[1];
    const float* W_hh1 = (const float*)d_in[2];
    const float* b_ih1 = (const float*)d_in[3];
    const float* b_hh1 = (const float*)d_in[4];
    const float* W_ih2 = (const float*)d_in[5];
    const float* W_hh2 = (const float*)d_in[6];
    const float* b_ih2 = (const float*)d_in[7];
    const float* b_hh2 = (const float*)d_in[8];
    const float* W_lin = (const float*)d_in[9];
    const float* b_lin = (const float*)d_in[10];

    const int bsz = in_sizes[0] / TSEQ;   // 4096

    hipLaunchKernelGGL(lstm_mfma_kernel, dim3(bsz / NB), dim3(NTHREADS), 0, stream,
                       input, W_ih1, W_hh1, b_ih1, b_hh1,
                       W_ih2, W_hh2, b_ih2, b_hh2, W_lin, b_lin,
                       (float*)d_out);
}

// Round 16
// 412.814 us; speedup vs baseline: 2.1911x; 2.1911x over previous
//
#include <hip/hip_runtime.h>

#define TSEQ 512
#define FUT  16
#define OT   (TSEQ + FUT)
#define NB   16
#define NWAVE 13
#define NTHREADS (NWAVE * 64)
#define OBS  20

typedef _Float16 f16x8 __attribute__((ext_vector_type(8)));
typedef float    f32x4 __attribute__((ext_vector_type(4)));

#define NL2E  (-1.44269504089f)
#define N2L2E (-2.88539008178f)

__device__ __forceinline__ f32x4 mfma16(f16x8 a, f16x8 b, f32x4 c) {
    return __builtin_amdgcn_mfma_f32_16x16x32_f16(a, b, c, 0, 0, 0);
}

// single-instruction 2^x (v_exp_f32)
__device__ __forceinline__ float exp2fast(float x) {
#if __has_builtin(__builtin_amdgcn_exp2f)
    return __builtin_amdgcn_exp2f(x);
#else
    float r;
    asm("v_exp_f32 %0, %1\n\ts_nop 1" : "=v"(r) : "v"(x));
    return r;
#endif
}

// main-loop barrier: order LDS only (lgkmcnt); do NOT drain vmcnt -> the
// x-loads / o-stores stay in flight across barriers (their waits land at use).
#define BAR_LGKM() asm volatile("s_waitcnt lgkmcnt(0)\n\ts_barrier" ::: "memory")

// acc pre-scaled at weight-load: i,f,o rows by -log2e; g row by -2log2e.
// sig(x) = rcp(1+E), tanh via (1-E)/(1+E); fused denominators: 5 exp + 3 rcp.
__device__ __forceinline__ float cell2(const f32x4 acc, float& c) {
    const float Ei = exp2fast(acc[0]);          // e^-i
    const float Ef = exp2fast(acc[1]);          // e^-f
    const float Eg = exp2fast(acc[2]);          // e^-2g
    const float Eo = exp2fast(acc[3]);          // e^-o
    const float sf   = __builtin_amdgcn_rcpf(1.0f + Ef);
    const float sitg = (1.0f - Eg) * __builtin_amdgcn_rcpf((1.0f + Ei) * (1.0f + Eg));
    c = fmaf(sf, c, sitg);
    const float Ec = exp2fast(c * N2L2E);       // e^-2c
    return (1.0f - Ec) * __builtin_amdgcn_rcpf((1.0f + Eo) * (1.0f + Ec));
}

__global__ __launch_bounds__(NTHREADS, 1) void lstm_mfma_kernel(
    const float* __restrict__ input,   // [B, 512]
    const float* __restrict__ W_ih1,   // [204,1]
    const float* __restrict__ W_hh1,   // [204,51]
    const float* __restrict__ b_ih1,
    const float* __restrict__ b_hh1,
    const float* __restrict__ W_ih2,   // [204,51]
    const float* __restrict__ W_hh2,   // [204,51]
    const float* __restrict__ b_ih2,
    const float* __restrict__ b_hh2,
    const float* __restrict__ W_lin,   // [1,51]
    const float* __restrict__ b_lin,
    float* __restrict__ out)           // [B, 528]
{
    const int tid  = threadIdx.x;
    const int w    = tid >> 6;    // wave id (0..12)
    const int lane = tid & 63;
    const int n    = lane & 15;   // batch col (B operand) / A row index
    const int q    = lane >> 4;   // k-group; also unit-in-tile this lane updates
    const int b0   = blockIdx.x * NB;
    // tile permutation: swap tiles 11<->12 so the duty-laden light tile 12
    // (W_lin row, o-duty, x-duty) sits on wave 11 -> SIMD3 (3-wave SIMD),
    // leaving the laggard SIMD0 (waves 0,4,8,12) pure symmetric compute.
    const int tw   = (w == 11) ? 12 : (w == 12) ? 11 : w;

    // activations (hi f16) in MFMA B-fragment layout, parity double-buffered
    // logical k at [k>>5][n + 16*((k&31)>>3)][k&7]; H1 k=51 slot carries x_t
    __shared__ _Float16 H1[2][2][64][8] __attribute__((aligned(16)));
    __shared__ _Float16 H2[2][2][64][8] __attribute__((aligned(16)));
    __shared__ float OB[2][16][OBS] __attribute__((aligned(16)));

    // ---- A-operand (weights) fragments: lane holds A row m = n ----
    const int ru  = 4 * tw + (n >> 2);             // unit of this A row
    const bool rv = (ru < 51);
    const int R   = 51 * (n & 3) + (rv ? ru : 50); // PyTorch row = 51*gtype + unit
    const bool olin_row = (tw == 12) && (n == 12); // pad row repurposed -> W_lin
    const float rsc = ((n & 3) == 2) ? N2L2E : NL2E;  // exp2 fold (g row: -2log2e)

    f16x8 W1h[2], W1l[2], W2h[4], W2l[4];
#pragma unroll
    for (int s = 0; s < 2; ++s) {
#pragma unroll
        for (int e = 0; e < 8; ++e) {
            const int k = 32 * s + 8 * q + e;
            float wv = 0.0f;
            if (rv) {
                if (k < 51)       wv = rsc * W_hh1[R * 51 + k];
                else if (k == 51) wv = rsc * W_ih1[R];        // x column (LDS k51 slot)
            }
            const _Float16 hi = (_Float16)wv;
            W1h[s][e] = hi;
            W1l[s][e] = (_Float16)(wv - (float)hi);
        }
    }
#pragma unroll
    for (int s = 0; s < 4; ++s) {
#pragma unroll
        for (int e = 0; e < 8; ++e) {
            const int k = 32 * s + 8 * q + e;
            float wv = 0.0f;
            if (rv) {
                if (k < 51)                  wv = rsc * W_ih2[R * 51 + k];        // h1 block
                else if (k >= 64 && k < 115) wv = rsc * W_hh2[R * 51 + (k - 64)]; // h2 block
            } else if (olin_row) {
                if (k >= 64 && k < 115)      wv = W_lin[k - 64];   // unscaled
            }
            const _Float16 hi = (_Float16)wv;
            W2h[s][e] = hi;
            W2l[s][e] = (_Float16)(wv - (float)hi);
        }
    }

    // ---- update-side constants: this lane updates (batch n, unit uu=4tw+q) ----
    const int uu = 4 * tw + q;
    const bool ustore = (uu < 51);
    const bool oduty = (tw == 12) && (q == 3);     // a2[0] = o(batch n) on these lanes
    f32x4 bias1v, bias2v;
#pragma unroll
    for (int r = 0; r < 4; ++r) {
        const int row = 51 * r + (ustore ? uu : 50);
        const float s = (r == 2) ? N2L2E : NL2E;
        bias1v[r] = ustore ? s * (b_ih1[row] + b_hh1[row]) : 0.0f;
        bias2v[r] = ustore ? s * (b_ih2[row] + b_hh2[row]) : 0.0f;
    }
    const float blin = b_lin[0];
    if (oduty) bias2v[0] = blin;                   // C-init of the W_lin row
    const float wlin = ustore ? W_lin[uu] : 0.0f;  // tail-only reduction weight
    // pad lanes (uu==51) redirect to fake unit 60 (zero-weight k-slot) ->
    // unconditional stores.
    const int uuX = ustore ? uu : 60;
    const int us = uuX >> 5;
    const int lp = n + 16 * ((uuX & 31) >> 3);
    const int ue = uuX & 7;

    // ---- zero activation LDS ----
    {
        const f16x8 zz = {0, 0, 0, 0, 0, 0, 0, 0};
        f16x8* p1 = (f16x8*)&H1[0][0][0][0];
        f16x8* p2 = (f16x8*)&H2[0][0][0][0];
        for (int i = tid; i < 2 * 2 * 64; i += NTHREADS) { p1[i] = zz; p2[i] = zz; }
    }
    __syncthreads();

    float c1 = 0.0f, c2 = 0.0f;

    // x chunk registers live on the tile-12 wave (w11 -> SIMD3) q2 lanes
    f32x4 xv = {0, 0, 0, 0}, xvn = {0, 0, 0, 0};
    if (tw == 12 && q == 2) {
        xv  = *(const f32x4*)&input[(b0 + n) * TSEQ + 0];
        xvn = *(const f32x4*)&input[(b0 + n) * TSEQ + 4];
    }

    // batched o-store buffer (meaningful on oduty lanes only)
    f32x4 obuf = {0, 0, 0, 0};

    // ---- prologue: phase 0 = L1(0) with h1_{-1}=0; seed x_1 into H1[1] ----
    {
        if (tw == 12 && q == 2) H1[1][1][32 + n][3] = (_Float16)xv[1];  // x_1
        const float x0 = input[(b0 + n) * TSEQ + 0];
        f16x8 xf = {0,0,0,0,0,0,0,0};
        if (q == 2) xf[3] = (_Float16)x0;
        f32x4 a1 = mfma16(W1h[1], xf, bias1v);
        a1 = mfma16(W1l[1], xf, a1);
        const float h1n = cell2(a1, c1);
        H1[1][us][lp][ue] = (_Float16)h1n;   // h1_0 -> buf[1]
    }
    __syncthreads();

    // ---- main loop: phase t does L1(t) || L2(t-1), 1 lgkm-only barrier ----
    // read h1 frags -> a1 chain -> read h2 frags -> a2 chain (halves the LDS
    // queue depth ahead of each wave's first dependent MFMA).
#define PHASE(t_, W_, ROT_, OSL_, OSTORE_, FLUSH_, LOADN_, XW_)                \
    {                                                                          \
        const int p_  = (t_) & 1;                                              \
        const int pn_ = p_ ^ 1;                                                \
        const f16x8 h1k0 = *(const f16x8*)&H1[p_][0][lane][0];                 \
        const f16x8 h1k1 = *(const f16x8*)&H1[p_][1][lane][0];                 \
        if (tw == 12) {                                                        \
            if (ROT_) xv = xvn;                                                \
            if ((LOADN_) && q == 2)                                            \
                xvn = *(const f32x4*)&input[(b0 + n) * TSEQ + (t_) + 3];       \
            if ((XW_) && q == 2)                                               \
                H1[pn_][1][32 + n][3] = (_Float16)xv[W_];                      \
        }                                                                      \
        f32x4 a1 = mfma16(W1h[0], h1k0, bias1v);                               \
        a1 = mfma16(W1l[0], h1k0, a1);                                         \
        a1 = mfma16(W1h[1], h1k1, a1);                                         \
        a1 = mfma16(W1l[1], h1k1, a1);                                         \
        const f16x8 h2k0 = *(const f16x8*)&H2[p_][0][lane][0];                 \
        const f16x8 h2k1 = *(const f16x8*)&H2[p_][1][lane][0];                 \
        f32x4 a2 = mfma16(W2h[0], h1k0, bias2v);                               \
        a2 = mfma16(W2l[0], h1k0, a2);                                         \
        a2 = mfma16(W2h[1], h1k1, a2);                                         \
        a2 = mfma16(W2l[1], h1k1, a2);                                         \
        a2 = mfma16(W2h[2], h2k0, a2);                                         \
        a2 = mfma16(W2l[2], h2k0, a2);                                         \
        a2 = mfma16(W2h[3], h2k1, a2);                                         \
        a2 = mfma16(W2l[3], h2k1, a2);                                         \
        const float h1n = cell2(a1, c1);                                       \
        H1[pn_][us][lp][ue] = (_Float16)h1n;                                   \
        if (OSTORE_) obuf[OSL_] = a2[0];                                       \
        if ((FLUSH_) && oduty)                                                 \
            *reinterpret_cast<f32x4*>(&out[(b0 + n) * OT + (t_) - 5]) = obuf;  \
        const float h2n = cell2(a2, c2);                                       \
        H2[pn_][us][lp][ue] = (_Float16)h2n;                                   \
        BAR_LGKM();                                                            \
    }

    //      t    W  ROT OSL OST FLU LOD XW
    PHASE(  1,   2, 0,  0,  0,  0,  0,  1)   // writes x_2
    for (int tb = 2; tb + 3 <= 505; tb += 4) {
        PHASE(tb + 0, 3, 0, 0, 1, 0, 0, 1)   // o_{tb-2} slot0; writes x_{tb+1}
        PHASE(tb + 1, 0, 1, 1, 1, 0, 0, 1)   // rotate; writes x_{tb+2}
        PHASE(tb + 2, 1, 0, 2, 1, 0, 0, 1)
        PHASE(tb + 3, 2, 0, 3, 1, 1, 1, 1)   // flush o_{tb-2..tb+1}; load chunk
    }
    PHASE(506, 3, 0, 0, 1, 0, 0, 1)          // o_504; writes x_507
    PHASE(507, 0, 1, 1, 1, 0, 0, 1)          // o_505; rotate; writes x_508
    PHASE(508, 1, 0, 2, 1, 0, 0, 1)          // o_506; writes x_509
    PHASE(509, 2, 0, 3, 1, 1, 0, 1)          // o_507 + flush o_504..507; writes x_510
    PHASE(510, 3, 0, 0, 1, 0, 0, 1)          // o_508 -> slot0; writes x_511
    PHASE(511, 0, 0, 1, 1, 0, 0, 0)          // o_509 -> slot1; no x write
#undef PHASE

    if (oduty) {                             // flush o_508, o_509
        out[(b0 + n) * OT + 508] = obuf[0];
        out[(b0 + n) * OT + 509] = obuf[1];
    }

    // ---- tail: autoregressive steps t = 512..527 (x_t = o_{t-1}) ----
    for (int t = TSEQ; t < OT; ++t) {
        const int p  = t & 1;
        const int pn = p ^ 1;

        // .a: L2(t-1) -> h2_{t-1}; OB partials; o_510 via MFMA row at t==512
        const f16x8 h1k0 = *(const f16x8*)&H1[p][0][lane][0];
        f16x8 h1k1       = *(const f16x8*)&H1[p][1][lane][0];
        const f16x8 h2k0 = *(const f16x8*)&H2[p][0][lane][0];
        const f16x8 h2k1 = *(const f16x8*)&H2[p][1][lane][0];
        f32x4 a2 = mfma16(W2h[0], h1k0, bias2v);
        a2 = mfma16(W2l[0], h1k0, a2);
        a2 = mfma16(W2h[1], h1k1, a2);
        a2 = mfma16(W2l[1], h1k1, a2);
        a2 = mfma16(W2h[2], h2k0, a2);
        a2 = mfma16(W2l[2], h2k0, a2);
        a2 = mfma16(W2h[3], h2k1, a2);
        a2 = mfma16(W2l[3], h2k1, a2);
        if (oduty && t == TSEQ) out[(b0 + n) * OT + (TSEQ - 2)] = a2[0];  // o_510
        const float h2n = cell2(a2, c2);
        H2[pn][us][lp][ue] = (_Float16)h2n;
        float po = h2n * wlin;
        po += __shfl_xor(po, 16, 64);
        po += __shfl_xor(po, 32, 64);
        if (lane < 16) OB[p][lane][tw] = po;
        __syncthreads();

        // .b: finalize o_{t-1} (q2 lanes, redundant per wave); feedback; L1(t)
        float xcur = 0.0f;
        if (q == 2) {
            const float* ob = &OB[p][n][0];
            const f32x4 s0 = *(const f32x4*)&ob[0];
            const f32x4 s1 = *(const f32x4*)&ob[4];
            const f32x4 s2 = *(const f32x4*)&ob[8];
            const float o = ((s0[0] + s0[1]) + (s0[2] + s0[3]))
                          + ((s1[0] + s1[1]) + (s1[2] + s1[3]))
                          + ((s2[0] + s2[1]) + (s2[2] + s2[3])) + ob[12] + blin;
            if (w == 0) out[(b0 + n) * OT + (t - 1)] = o;
            xcur = o;
        }
        if (q == 2) h1k1[3] = (_Float16)xcur;   // patch x_t (f16)
        f32x4 a1 = mfma16(W1h[0], h1k0, bias1v);
        a1 = mfma16(W1l[0], h1k0, a1);
        a1 = mfma16(W1h[1], h1k1, a1);
        a1 = mfma16(W1l[1], h1k1, a1);
        const float h1n = cell2(a1, c1);
        H1[pn][us][lp][ue] = (_Float16)h1n;
        __syncthreads();
    }

    // ---- final: L2(527) -> h2_527 -> o_527 ----
    {
        const f16x8 h1k0 = *(const f16x8*)&H1[0][0][lane][0];
        const f16x8 h1k1 = *(const f16x8*)&H1[0][1][lane][0];
        const f16x8 h2k0 = *(const f16x8*)&H2[0][0][lane][0];
        const f16x8 h2k1 = *(const f16x8*)&H2[0][1][lane][0];
        f32x4 a2 = mfma16(W2h[0], h1k0, bias2v);
        a2 = mfma16(W2l[0], h1k0, a2);
        a2 = mfma16(W2h[1], h1k1, a2);
        a2 = mfma16(W2l[1], h1k1, a2);
        a2 = mfma16(W2h[2], h2k0, a2);
        a2 = mfma16(W2l[2], h2k0, a2);
        a2 = mfma16(W2h[3], h2k1, a2);
        a2 = mfma16(W2l[3], h2k1, a2);
        const float h2n = cell2(a2, c2);
        float po = h2n * wlin;
        po += __shfl_xor(po, 16, 64);
        po += __shfl_xor(po, 32, 64);
        if (lane < 16) OB[0][lane][tw] = po;
        __syncthreads();
        if (w == 0 && lane < 16) {
            const float* ob = &OB[0][lane][0];
            const f32x4 s0 = *(const f32x4*)&ob[0];
            const f32x4 s1 = *(const f32x4*)&ob[4];
            const f32x4 s2 = *(const f32x4*)&ob[8];
            out[(b0 + lane) * OT + (OT - 1)] =
                ((s0[0] + s0[1]) + (s0[2] + s0[3])) +
                ((s1[0] + s1[1]) + (s1[2] + s1[3])) +
                ((s2[0] + s2[1]) + (s2[2] + s2[3])) + ob[12] + blin;
        }
    }
}

extern "C" void kernel_launch(void* const* d_in, const int* in_sizes, int n_in,
                              void* d_out, int out_size, void* d_ws, size_t ws_size,
                              hipStream_t stream) {
    const float* input = (const float*)d_in[0];
    const float* W_ih1 = (const float*)d_in[1];
    const float* W_hh1 = (const float*)d_in[2];
    const float* b_ih1 = (const float*)d_in[3];
    const float* b_hh1 = (const float*)d_in[4];
    const float* W_ih2 = (const float*)d_in[5];
    const float* W_hh2 = (const float*)d_in[6];
    const float* b_ih2 = (const float*)d_in[7];
    const float* b_hh2 = (const float*)d_in[8];
    const float* W_lin = (const float*)d_in[9];
    const float* b_lin = (const float*)d_in[10];

    const int bsz = in_sizes[0] / TSEQ;   // 4096

    hipLaunchKernelGGL(lstm_mfma_kernel, dim3(bsz / NB), dim3(NTHREADS), 0, stream,
                       input, W_ih1, W_hh1, b_ih1, b_hh1,
                       W_ih2, W_hh2, b_ih2, b_hh2, W_lin, b_lin,
                       (float*)d_out);
}